// Round 3
// baseline (433.687 us; speedup 1.0000x reference)
//
#include <hip/hip_runtime.h>
#include <cstdint>
#include <cstddef>

// Problem constants (fixed shapes from setup_inputs)
#define IN_DIM  1024
#define OUT_DIM 1024
#define NB      7
#define KTOT    8192   // interleaved: k = i*8 + {x, basis0..basis6}
#define BROWS   8192   // batch

typedef unsigned short u16;
typedef __attribute__((ext_vector_type(8))) short bf16x8;
typedef __attribute__((ext_vector_type(8))) unsigned short u16x8;
typedef __attribute__((ext_vector_type(4))) float f32x4;

__device__ __forceinline__ u16 f2bf(float f) {
    union { float f; unsigned int u; } v; v.f = f;
    unsigned int r = (v.u + 0x7fffu + ((v.u >> 16) & 1u)) >> 16;  // RTN-even
    return (u16)r;
}

__device__ __forceinline__ void gl_lds16(const u16* g, u16* l) {
    __builtin_amdgcn_global_load_lds(
        (const __attribute__((address_space(1))) void*)g,
        (__attribute__((address_space(3))) void*)l,
        16, 0, 0);
}

// ---------------------------------------------------------------------------
// prep_wsw: Bt[o][i*8+0] = bf16(W[o][i]); Bt[o][i*8+1+k] = bf16(sw[i][o][k]).
__global__ __launch_bounds__(256) void prep_wsw(const float* __restrict__ sw,
                                                const float* __restrict__ W,
                                                u16* __restrict__ Bt) {
    __shared__ u16 S[8 * 256 * 8];               // [il][ol][slot], 32 KB
    const int i0 = blockIdx.x * 8;
    const int o0 = blockIdx.y * 256;
    const int t  = threadIdx.x;
    #pragma unroll
    for (int il = 0; il < 8; ++il) {
        const float* src = sw + ((size_t)(i0 + il) * OUT_DIM + o0) * NB;
        for (int c = t; c < 256 * NB; c += 256) {
            int ol = c / 7, k = c - ol * 7;
            S[(il * 256 + ol) * 8 + 1 + k] = f2bf(src[c]);
        }
    }
    for (int c = t; c < 2048; c += 256) {
        int ol = c >> 3, il = c & 7;
        S[(il * 256 + ol) * 8] = f2bf(W[(size_t)(o0 + ol) * IN_DIM + i0 + il]);
    }
    __syncthreads();
    for (int c = t; c < 2048; c += 256) {
        int ol = c >> 3, il = c & 7;   // consecutive t -> contiguous 16B writes
        *(u16x8*)&Bt[(size_t)(o0 + ol) * KTOT + (size_t)(i0 + il) * 8] =
            *(const u16x8*)&S[(il * 256 + ol) * 8];
    }
}

// ---------------------------------------------------------------------------
// prep_a: A[b][i*8+0] = bf16(x[b][i]); A[b][i*8+1+k] = bf16(basis_k(tanh(x))).
__global__ __launch_bounds__(256) void prep_a(const float* __restrict__ x,
                                              u16* __restrict__ A, int row0) {
    int gid = blockIdx.x * 256 + threadIdx.x;
    int b = gid >> 10;
    int i = gid & 1023;
    float xv = x[(size_t)(row0 + b) * IN_DIM + i];

    float t = tanhf(xv);
    t = fminf(fmaxf(t, -1.f), 1.f);

    const float kn[11] = {-1.f, -0.8f, -0.6f, -0.4f, -0.2f, 0.f,
                           0.2f, 0.4f, 0.6f, 0.8f, 1.f};
    float bb[8];
    #pragma unroll
    for (int j = 0; j < 7; ++j)
        bb[j] = (t >= kn[j] && t < kn[j + 1]) ? 1.f : 0.f;
    bb[7] = 0.f;

    const float rcp[4] = {0.f, 5.f, 2.5f, 5.f / 3.f};  // 1/(0.2*d)
    #pragma unroll
    for (int d = 1; d <= 3; ++d) {
        #pragma unroll
        for (int j = 0; j < 7; ++j) {
            float left  = (t - kn[j]) * rcp[d];
            float right = (kn[j + d + 1] - t) * rcp[d];
            bb[j] = left * bb[j] + right * bb[j + 1];
        }
    }
    u16x8 outv;
    outv[0] = f2bf(xv);
    #pragma unroll
    for (int k = 0; k < NB; ++k) outv[1 + k] = f2bf(bb[k]);
    *(u16x8*)&A[(size_t)b * KTOT + (size_t)i * 8] = outv;
}

// ---------------------------------------------------------------------------
// gemm_bt v3: A staged via global_load_lds with XOR chunk swizzle
// (phys_chunk = q ^ ((row>>1)&3), absorbed into the global source address;
// kills the 16-bank row-stride aliasing). B fragments loaded directly
// global->VGPR (Bt is L1/L2/LLC resident; removes half the LDS traffic and
// half the staging drain), software-pipelined one iteration ahead.
__global__ __launch_bounds__(256) void gemm_bt(const u16* __restrict__ A,
                                               const u16* __restrict__ Bt,
                                               const float* __restrict__ bias,
                                               float* __restrict__ C) {
    __shared__ __align__(16) u16 As[128 * 32];   // 8 KB
    const int t = threadIdx.x;
    const int L = t & 63;
    const int w = t >> 6;
    const int wm = w & 1, wn = w >> 1;

    // XCD swizzle: all 8 n-tiles of one m-tile share blockIdx%8 (same XCD)
    const int Lid = blockIdx.x;
    const int r   = Lid & 7;
    const int q   = Lid >> 3;
    const int n_t = q & 7;
    const int m_t = r + 8 * (q >> 3);
    const int m0 = m_t * 128;
    const int n0 = n_t * 128;

    f32x4 acc[4][4] = {};

    // A staging: thread t -> row srow & srow+64, phys chunk p=t&3.
    // Global logical chunk fetched = p ^ ((srow>>1)&3)  (XOR swizzle).
    const int srow = t >> 2;
    const int qsw  = (t & 3) ^ ((srow >> 1) & 3);
    const u16* gA0 = A + (size_t)(m0 + srow) * KTOT + qsw * 8;
    const u16* gA1 = gA0 + (size_t)64 * KTOT;
    u16* lA0 = &As[t * 8];
    u16* lA1 = &As[2048 + t * 8];

    const int lm = L & 15;
    // A-frag read: row R, logical chunk q=L>>4 lives at phys chunk q^((lm>>1)&3)
    // ((R>>1)&3 == (lm>>1)&3 since R = 16*... + lm)
    const int cq = ((L >> 4) ^ ((lm >> 1) & 3)) * 8;

    // B fragment pointers: row n0+wn*64+ni*16+lm, k-offset (L>>4)*8
    const u16* gB[4];
    #pragma unroll
    for (int ni = 0; ni < 4; ++ni)
        gB[ni] = Bt + (size_t)(n0 + wn * 64 + ni * 16 + lm) * KTOT + (L >> 4) * 8;

    bf16x8 bcur[4], bnext[4];
    #pragma unroll
    for (int ni = 0; ni < 4; ++ni) bcur[ni] = *(const bf16x8*)gB[ni];

    for (int ko = 0; ko < KTOT; ko += 32) {
        __syncthreads();
        gl_lds16(gA0 + ko, lA0);
        gl_lds16(gA1 + ko, lA1);
        if (ko + 32 < KTOT) {
            #pragma unroll
            for (int ni = 0; ni < 4; ++ni)
                bnext[ni] = *(const bf16x8*)(gB[ni] + ko + 32);
        }
        __syncthreads();

        bf16x8 af[4];
        #pragma unroll
        for (int mi = 0; mi < 4; ++mi)
            af[mi] = *(const bf16x8*)&As[(wm * 64 + mi * 16 + lm) * 32 + cq];
        #pragma unroll
        for (int mi = 0; mi < 4; ++mi)
            #pragma unroll
            for (int ni = 0; ni < 4; ++ni)
                acc[mi][ni] = __builtin_amdgcn_mfma_f32_16x16x32_bf16(
                    af[mi], bcur[ni], acc[mi][ni], 0, 0, 0);
        #pragma unroll
        for (int ni = 0; ni < 4; ++ni) bcur[ni] = bnext[ni];
    }

    // epilogue: C/D layout col=lane&15, row=(lane>>4)*4+reg (m89-verified)
    const int r0 = (L >> 4) * 4;
    #pragma unroll
    for (int ni = 0; ni < 4; ++ni) {
        int col = n0 + wn * 64 + ni * 16 + lm;
        float bv = bias[col];
        #pragma unroll
        for (int mi = 0; mi < 4; ++mi) {
            int rb = m0 + wm * 64 + mi * 16 + r0;
            f32x4 v = acc[mi][ni];
            #pragma unroll
            for (int rr = 0; rr < 4; ++rr)
                C[(size_t)(rb + rr) * OUT_DIM + col] = v[rr] + bv;
        }
    }
}

// ---------------------------------------------------------------------------
extern "C" void kernel_launch(void* const* d_in, const int* in_sizes, int n_in,
                              void* d_out, int out_size, void* d_ws, size_t ws_size,
                              hipStream_t stream) {
    (void)in_sizes; (void)n_in; (void)out_size;
    const float* x    = (const float*)d_in[0];
    const float* sw   = (const float*)d_in[1];
    const float* W    = (const float*)d_in[2];
    const float* bias = (const float*)d_in[3];
    float* out = (float*)d_out;

    const size_t btBytes = (size_t)OUT_DIM * KTOT * 2;     // 16 MB
    u16* Bt = (u16*)d_ws;
    u16* A  = (u16*)((char*)d_ws + btBytes);

    prep_wsw<<<dim3(IN_DIM / 8, OUT_DIM / 256), 256, 0, stream>>>(sw, W, Bt);

    int nchunks = 1;
    if (ws_size < btBytes + (size_t)BROWS * KTOT * 2)       nchunks = 2;
    if (ws_size < btBytes + (size_t)(BROWS / 2) * KTOT * 2) nchunks = 4;
    if (ws_size < btBytes + (size_t)(BROWS / 4) * KTOT * 2) nchunks = 8;
    const int rows = BROWS / nchunks;

    for (int c = 0; c < nchunks; ++c) {
        int row0 = c * rows;
        prep_a<<<rows * 4, 256, 0, stream>>>(x, A, row0);
        gemm_bt<<<dim3(8 * (rows / 128)), 256, 0, stream>>>(
            A, Bt, bias, out + (size_t)row0 * OUT_DIM);
    }
}

// Round 4
// 338.388 us; speedup vs baseline: 1.2816x; 1.2816x over previous
//
#include <hip/hip_runtime.h>
#include <cstdint>
#include <cstddef>

// Problem constants (fixed shapes from setup_inputs)
#define IN_DIM  1024
#define OUT_DIM 1024
#define NB      7
#define KTOT    8192   // interleaved: k = i*8 + {x, basis0..basis6}
#define BROWS   8192   // batch

// Fragment-major layout: element (m, k) lives at
//   tile = (m>>4)*256 + (k>>5), lane = (m&15) + 16*((k>>3)&3), byte = 2*(k&7)
//   u16 index = tile*512 + lane*8 + (k&7)
// One (m, i) pair's 8 values (k = 8i..8i+7) = exactly one lane's 16B chunk.

typedef unsigned short u16;
typedef __attribute__((ext_vector_type(8))) short bf16x8;
typedef __attribute__((ext_vector_type(8))) unsigned short u16x8;
typedef __attribute__((ext_vector_type(4))) float f32x4;

__device__ __forceinline__ u16 f2bf(float f) {
    union { float f; unsigned int u; } v; v.f = f;
    unsigned int r = (v.u + 0x7fffu + ((v.u >> 16) & 1u)) >> 16;  // RTN-even
    return (u16)r;
}

// ---------------------------------------------------------------------------
// prep_wsw: Bf fragment-major from W (k = i*8) and sw (k = i*8+1+kk).
// Tile: 8 i x 256 o. Output: 32 micro-tiles of 1 KB, coalesced u16x8 stores.
__global__ __launch_bounds__(256) void prep_wsw(const float* __restrict__ sw,
                                                const float* __restrict__ W,
                                                u16* __restrict__ Bf) {
    __shared__ u16 S[8 * 256 * 8];               // [il][ol][slot], 32 KB
    const int i0 = blockIdx.x * 8;
    const int o0 = blockIdx.y * 256;
    const int t  = threadIdx.x;
    #pragma unroll
    for (int il = 0; il < 8; ++il) {
        const float* src = sw + ((size_t)(i0 + il) * OUT_DIM + o0) * NB;
        for (int c = t; c < 256 * NB; c += 256) {
            int ol = c / 7, k = c - ol * 7;
            S[(il * 256 + ol) * 8 + 1 + k] = f2bf(src[c]);
        }
    }
    for (int c = t; c < 2048; c += 256) {
        int ol = c >> 3, il = c & 7;
        S[(il * 256 + ol) * 8] = f2bf(W[(size_t)(o0 + ol) * IN_DIM + i0 + il]);
    }
    __syncthreads();
    // 32 tiles (16 o-tiles x 2 k-tiles) x 64 lanes
    for (int f = t; f < 2048; f += 256) {
        int lane = f & 63;
        int tl   = f >> 6;            // 0..31
        int c16l = tl >> 1;           // o-tile within block
        int ktl  = tl & 1;            // k32-tile within block
        int ol   = c16l * 16 + (lane & 15);
        int il   = ktl * 4 + (lane >> 4);
        size_t dst = ((size_t)((o0 >> 4) + c16l) * 256 + (i0 >> 2) + ktl) * 512
                   + (size_t)lane * 8;
        *(u16x8*)&Bf[dst] = *(const u16x8*)&S[(il * 256 + ol) * 8];
    }
}

// ---------------------------------------------------------------------------
// prep_a: fragment-major A. Block = 16 b-rows x 16 i-values; thread
// (bl = t&15, iv = t>>4) computes x[b0+bl][i0+iv] -> one u16x8 chunk.
// A wave writes exactly one contiguous 1 KB micro-tile (fully coalesced).
__global__ __launch_bounds__(256) void prep_a(const float* __restrict__ x,
                                              u16* __restrict__ Af, int row0) {
    const int bt = blockIdx.x >> 6;     // b-tile (16 rows)
    const int it = blockIdx.x & 63;     // i-tile (16 i's)
    const int bl = threadIdx.x & 15;
    const int iv = threadIdx.x >> 4;
    const int b  = bt * 16 + bl;        // local row within chunk
    const int i  = it * 16 + iv;
    float xv = x[(size_t)(row0 + b) * IN_DIM + i];

    float t = tanhf(xv);
    t = fminf(fmaxf(t, -1.f), 1.f);

    const float kn[11] = {-1.f, -0.8f, -0.6f, -0.4f, -0.2f, 0.f,
                           0.2f, 0.4f, 0.6f, 0.8f, 1.f};
    float bb[8];
    #pragma unroll
    for (int j = 0; j < 7; ++j)
        bb[j] = (t >= kn[j] && t < kn[j + 1]) ? 1.f : 0.f;
    bb[7] = 0.f;

    const float rcp[4] = {0.f, 5.f, 2.5f, 5.f / 3.f};  // 1/(0.2*d)
    #pragma unroll
    for (int d = 1; d <= 3; ++d) {
        #pragma unroll
        for (int j = 0; j < 7; ++j) {
            float left  = (t - kn[j]) * rcp[d];
            float right = (kn[j + d + 1] - t) * rcp[d];
            bb[j] = left * bb[j] + right * bb[j + 1];
        }
    }
    u16x8 outv;
    outv[0] = f2bf(xv);
    #pragma unroll
    for (int k = 0; k < NB; ++k) outv[1 + k] = f2bf(bb[k]);

    const int kt   = (i >> 2);                 // k32 tile index
    const int lane = bl + 16 * (i & 3);
    *(u16x8*)&Af[((size_t)bt * 256 + kt) * 512 + (size_t)lane * 8] = outv;
}

// ---------------------------------------------------------------------------
// gemm_bt v4: ZERO LDS, zero barriers. Both operands read directly
// global->VGPR from fragment-major layout: each load is 64 lanes x 16 B
// contiguous (1 KB, the ideal coalesced pattern). Software-pipelined by 1
// k-step; compiler schedules vmcnt. XCD swizzle keeps A-tile L2-local.
__global__ __launch_bounds__(256) void gemm_bt(const u16* __restrict__ Af,
                                               const u16* __restrict__ Bf,
                                               const float* __restrict__ bias,
                                               float* __restrict__ C) {
    const int t = threadIdx.x;
    const int L = t & 63;
    const int w = t >> 6;
    const int wm = w & 1, wn = w >> 1;

    // XCD swizzle: all 8 n-tiles of one m-tile share blockIdx%8 (same XCD)
    const int Lid = blockIdx.x;
    const int r   = Lid & 7;
    const int q   = Lid >> 3;
    const int n_t = q & 7;
    const int m_t = r + 8 * (q >> 3);

    f32x4 acc[4][4] = {};

    // Per-fragment base pointers at kt=0; advance by 512 u16 per k-step.
    const u16* aP[4];
    const u16* bP[4];
    #pragma unroll
    for (int mi = 0; mi < 4; ++mi)
        aP[mi] = Af + (size_t)(m_t * 8 + wm * 4 + mi) * (256 * 512) + (size_t)L * 8;
    #pragma unroll
    for (int ni = 0; ni < 4; ++ni)
        bP[ni] = Bf + (size_t)(n_t * 8 + wn * 4 + ni) * (256 * 512) + (size_t)L * 8;

    bf16x8 a0[4], b0[4], a1[4], b1[4];
    #pragma unroll
    for (int mi = 0; mi < 4; ++mi) a0[mi] = *(const bf16x8*)aP[mi];
    #pragma unroll
    for (int ni = 0; ni < 4; ++ni) b0[ni] = *(const bf16x8*)bP[ni];

    for (int kt = 0; kt < 256; kt += 2) {
        // prefetch kt+1
        if (kt + 1 < 256) {
            #pragma unroll
            for (int mi = 0; mi < 4; ++mi)
                a1[mi] = *(const bf16x8*)(aP[mi] + (size_t)(kt + 1) * 512);
            #pragma unroll
            for (int ni = 0; ni < 4; ++ni)
                b1[ni] = *(const bf16x8*)(bP[ni] + (size_t)(kt + 1) * 512);
        }
        #pragma unroll
        for (int mi = 0; mi < 4; ++mi)
            #pragma unroll
            for (int ni = 0; ni < 4; ++ni)
                acc[mi][ni] = __builtin_amdgcn_mfma_f32_16x16x32_bf16(
                    a0[mi], b0[ni], acc[mi][ni], 0, 0, 0);
        // prefetch kt+2
        if (kt + 2 < 256) {
            #pragma unroll
            for (int mi = 0; mi < 4; ++mi)
                a0[mi] = *(const bf16x8*)(aP[mi] + (size_t)(kt + 2) * 512);
            #pragma unroll
            for (int ni = 0; ni < 4; ++ni)
                b0[ni] = *(const bf16x8*)(bP[ni] + (size_t)(kt + 2) * 512);
        }
        #pragma unroll
        for (int mi = 0; mi < 4; ++mi)
            #pragma unroll
            for (int ni = 0; ni < 4; ++ni)
                acc[mi][ni] = __builtin_amdgcn_mfma_f32_16x16x32_bf16(
                    a1[mi], b1[ni], acc[mi][ni], 0, 0, 0);
    }

    // epilogue: C/D layout col=lane&15, row=(lane>>4)*4+reg (m89-verified)
    const int m0 = m_t * 128;
    const int n0 = n_t * 128;
    const int lm = L & 15;
    const int r0 = (L >> 4) * 4;
    #pragma unroll
    for (int ni = 0; ni < 4; ++ni) {
        int col = n0 + wn * 64 + ni * 16 + lm;
        float bv = bias[col];
        #pragma unroll
        for (int mi = 0; mi < 4; ++mi) {
            int rb = m0 + wm * 64 + mi * 16 + r0;
            f32x4 v = acc[mi][ni];
            #pragma unroll
            for (int rr = 0; rr < 4; ++rr)
                C[(size_t)(rb + rr) * OUT_DIM + col] = v[rr] + bv;
        }
    }
}

// ---------------------------------------------------------------------------
extern "C" void kernel_launch(void* const* d_in, const int* in_sizes, int n_in,
                              void* d_out, int out_size, void* d_ws, size_t ws_size,
                              hipStream_t stream) {
    (void)in_sizes; (void)n_in; (void)out_size;
    const float* x    = (const float*)d_in[0];
    const float* sw   = (const float*)d_in[1];
    const float* W    = (const float*)d_in[2];
    const float* bias = (const float*)d_in[3];
    float* out = (float*)d_out;

    const size_t btBytes = (size_t)OUT_DIM * KTOT * 2;     // 16 MB
    u16* Bf = (u16*)d_ws;
    u16* Af = (u16*)((char*)d_ws + btBytes);

    prep_wsw<<<dim3(IN_DIM / 8, OUT_DIM / 256), 256, 0, stream>>>(sw, W, Bf);

    int nchunks = 1;
    if (ws_size < btBytes + (size_t)BROWS * KTOT * 2)       nchunks = 2;
    if (ws_size < btBytes + (size_t)(BROWS / 2) * KTOT * 2) nchunks = 4;
    if (ws_size < btBytes + (size_t)(BROWS / 4) * KTOT * 2) nchunks = 8;
    const int rows = BROWS / nchunks;

    for (int c = 0; c < nchunks; ++c) {
        int row0 = c * rows;
        prep_a<<<rows * 4, 256, 0, stream>>>(x, Af, row0);
        gemm_bt<<<dim3(8 * (rows / 128)), 256, 0, stream>>>(
            Af, Bf, bias, out + (size_t)row0 * OUT_DIM);
    }
}

// Round 5
// 315.869 us; speedup vs baseline: 1.3730x; 1.0713x over previous
//
#include <hip/hip_runtime.h>
#include <cstdint>
#include <cstddef>

// Problem constants (fixed shapes from setup_inputs)
#define IN_DIM  1024
#define OUT_DIM 1024
#define NB      7
#define KTOT    8192   // interleaved: k = i*8 + {x, basis0..basis6}
#define BROWS   8192   // batch

typedef unsigned short u16;
typedef __attribute__((ext_vector_type(8))) short bf16x8;
typedef __attribute__((ext_vector_type(8))) unsigned short u16x8;
typedef __attribute__((ext_vector_type(4))) float f32x4;

__device__ __forceinline__ u16 f2bf(float f) {
    union { float f; unsigned int u; } v; v.f = f;
    unsigned int r = (v.u + 0x7fffu + ((v.u >> 16) & 1u)) >> 16;  // RTN-even
    return (u16)r;
}

__device__ __forceinline__ void gl_lds16(const u16* g, u16* l) {
    __builtin_amdgcn_global_load_lds(
        (const __attribute__((address_space(1))) void*)g,
        (__attribute__((address_space(3))) void*)l,
        16, 0, 0);
}

// ---------------------------------------------------------------------------
// prep_wsw: Bt[o][i*8+0] = bf16(W[o][i]); Bt[o][i*8+1+k] = bf16(sw[i][o][k]).
__global__ __launch_bounds__(256) void prep_wsw(const float* __restrict__ sw,
                                                const float* __restrict__ W,
                                                u16* __restrict__ Bt) {
    __shared__ u16 S[8 * 256 * 8];               // [il][ol][slot], 32 KB
    const int i0 = blockIdx.x * 8;
    const int o0 = blockIdx.y * 256;
    const int t  = threadIdx.x;
    #pragma unroll
    for (int il = 0; il < 8; ++il) {
        const float* src = sw + ((size_t)(i0 + il) * OUT_DIM + o0) * NB;
        for (int c = t; c < 256 * NB; c += 256) {
            int ol = c / 7, k = c - ol * 7;
            S[(il * 256 + ol) * 8 + 1 + k] = f2bf(src[c]);
        }
    }
    for (int c = t; c < 2048; c += 256) {
        int ol = c >> 3, il = c & 7;
        S[(il * 256 + ol) * 8] = f2bf(W[(size_t)(o0 + ol) * IN_DIM + i0 + il]);
    }
    __syncthreads();
    for (int c = t; c < 2048; c += 256) {
        int ol = c >> 3, il = c & 7;   // consecutive t -> contiguous 16B writes
        *(u16x8*)&Bt[(size_t)(o0 + ol) * KTOT + (size_t)(i0 + il) * 8] =
            *(const u16x8*)&S[(il * 256 + ol) * 8];
    }
}

// ---------------------------------------------------------------------------
// prep_a: A[b][i*8+0] = bf16(x[b][i]); A[b][i*8+1+k] = bf16(basis_k(tanh(x))).
// One aligned 16B store per thread, fully coalesced.
__global__ __launch_bounds__(256) void prep_a(const float* __restrict__ x,
                                              u16* __restrict__ A, int row0) {
    int gid = blockIdx.x * 256 + threadIdx.x;
    int b = gid >> 10;
    int i = gid & 1023;
    float xv = x[(size_t)(row0 + b) * IN_DIM + i];

    float t = tanhf(xv);
    t = fminf(fmaxf(t, -1.f), 1.f);

    const float kn[11] = {-1.f, -0.8f, -0.6f, -0.4f, -0.2f, 0.f,
                           0.2f, 0.4f, 0.6f, 0.8f, 1.f};
    float bb[8];
    #pragma unroll
    for (int j = 0; j < 7; ++j)
        bb[j] = (t >= kn[j] && t < kn[j + 1]) ? 1.f : 0.f;
    bb[7] = 0.f;

    const float rcp[4] = {0.f, 5.f, 2.5f, 5.f / 3.f};  // 1/(0.2*d)
    #pragma unroll
    for (int d = 1; d <= 3; ++d) {
        #pragma unroll
        for (int j = 0; j < 7; ++j) {
            float left  = (t - kn[j]) * rcp[d];
            float right = (kn[j + d + 1] - t) * rcp[d];
            bb[j] = left * bb[j] + right * bb[j + 1];
        }
    }
    u16x8 outv;
    outv[0] = f2bf(xv);
    #pragma unroll
    for (int k = 0; k < NB; ++k) outv[1 + k] = f2bf(bb[k]);
    *(u16x8*)&A[(size_t)b * KTOT + (size_t)i * 8] = outv;
}

// ---------------------------------------------------------------------------
// gemm_bt v5 = round-2 structure (LDS staging for BOTH operands — LDS is the
// VMEM de-duplicator) + XOR chunk swizzle on BOTH As and Bs (round-3 verified:
// SQ_LDS_BANK_CONFLICT 1.68e7 -> 0). Swizzle lives entirely in the GLOBAL
// source address of global_load_lds (LDS dest must stay lane-ordered):
//   phys_chunk(row, q) = q ^ ((row>>1) & 3)
// Readers: row R = 16*a + lm  =>  (R>>1)&3 == (lm>>1)&3, so
//   cq = ((L>>4) ^ ((lm>>1)&3)) * 8.
__global__ __launch_bounds__(256) void gemm_bt(const u16* __restrict__ A,
                                               const u16* __restrict__ Bt,
                                               const float* __restrict__ bias,
                                               float* __restrict__ C) {
    __shared__ __align__(16) u16 As[128 * 32];   // 8 KB
    __shared__ __align__(16) u16 Bs[128 * 32];   // 8 KB
    const int t = threadIdx.x;
    const int L = t & 63;
    const int w = t >> 6;
    const int wm = w & 1, wn = w >> 1;

    // XCD swizzle: all 8 n-tiles of one m-tile share blockIdx%8 (same XCD)
    const int Lid = blockIdx.x;
    const int r   = Lid & 7;
    const int q   = Lid >> 3;
    const int n_t = q & 7;
    const int m_t = r + 8 * (q >> 3);
    const int m0 = m_t * 128;
    const int n0 = n_t * 128;

    f32x4 acc[4][4] = {};

    // staging: thread t -> rows srow, srow+64; phys chunk t&3; global logical
    // chunk = (t&3) ^ ((srow>>1)&3)  (XOR swizzle)
    const int srow = t >> 2;
    const int qsw  = (t & 3) ^ ((srow >> 1) & 3);
    const u16* gA0 = A  + (size_t)(m0 + srow) * KTOT + qsw * 8;
    const u16* gA1 = gA0 + (size_t)64 * KTOT;
    const u16* gB0 = Bt + (size_t)(n0 + srow) * KTOT + qsw * 8;
    const u16* gB1 = gB0 + (size_t)64 * KTOT;
    u16* lA0 = &As[t * 8];  u16* lA1 = &As[2048 + t * 8];
    u16* lB0 = &Bs[t * 8];  u16* lB1 = &Bs[2048 + t * 8];

    const int lm = L & 15;
    const int cq = ((L >> 4) ^ ((lm >> 1) & 3)) * 8;  // swizzled chunk offset

    for (int ko = 0; ko < KTOT; ko += 32) {
        __syncthreads();
        gl_lds16(gA0 + ko, lA0);
        gl_lds16(gA1 + ko, lA1);
        gl_lds16(gB0 + ko, lB0);
        gl_lds16(gB1 + ko, lB1);
        __syncthreads();

        bf16x8 af[4], bfr[4];
        #pragma unroll
        for (int mi = 0; mi < 4; ++mi)
            af[mi] = *(const bf16x8*)&As[(wm * 64 + mi * 16 + lm) * 32 + cq];
        #pragma unroll
        for (int ni = 0; ni < 4; ++ni)
            bfr[ni] = *(const bf16x8*)&Bs[(wn * 64 + ni * 16 + lm) * 32 + cq];
        #pragma unroll
        for (int mi = 0; mi < 4; ++mi)
            #pragma unroll
            for (int ni = 0; ni < 4; ++ni)
                acc[mi][ni] = __builtin_amdgcn_mfma_f32_16x16x32_bf16(
                    af[mi], bfr[ni], acc[mi][ni], 0, 0, 0);
    }

    // epilogue: C/D layout col=lane&15, row=(lane>>4)*4+reg (m89-verified)
    const int r0 = (L >> 4) * 4;
    #pragma unroll
    for (int ni = 0; ni < 4; ++ni) {
        int col = n0 + wn * 64 + ni * 16 + lm;
        float bv = bias[col];
        #pragma unroll
        for (int mi = 0; mi < 4; ++mi) {
            int rb = m0 + wm * 64 + mi * 16 + r0;
            f32x4 v = acc[mi][ni];
            #pragma unroll
            for (int rr = 0; rr < 4; ++rr)
                C[(size_t)(rb + rr) * OUT_DIM + col] = v[rr] + bv;
        }
    }
}

// ---------------------------------------------------------------------------
extern "C" void kernel_launch(void* const* d_in, const int* in_sizes, int n_in,
                              void* d_out, int out_size, void* d_ws, size_t ws_size,
                              hipStream_t stream) {
    (void)in_sizes; (void)n_in; (void)out_size;
    const float* x    = (const float*)d_in[0];
    const float* sw   = (const float*)d_in[1];
    const float* W    = (const float*)d_in[2];
    const float* bias = (const float*)d_in[3];
    float* out = (float*)d_out;

    const size_t btBytes = (size_t)OUT_DIM * KTOT * 2;     // 16 MB
    u16* Bt = (u16*)d_ws;
    u16* A  = (u16*)((char*)d_ws + btBytes);

    prep_wsw<<<dim3(IN_DIM / 8, OUT_DIM / 256), 256, 0, stream>>>(sw, W, Bt);

    int nchunks = 1;
    if (ws_size < btBytes + (size_t)BROWS * KTOT * 2)       nchunks = 2;
    if (ws_size < btBytes + (size_t)(BROWS / 2) * KTOT * 2) nchunks = 4;
    if (ws_size < btBytes + (size_t)(BROWS / 4) * KTOT * 2) nchunks = 8;
    const int rows = BROWS / nchunks;

    for (int c = 0; c < nchunks; ++c) {
        int row0 = c * rows;
        prep_a<<<rows * 4, 256, 0, stream>>>(x, A, row0);
        gemm_bt<<<dim3(8 * (rows / 128)), 256, 0, stream>>>(
            A, Bt, bias, out + (size_t)row0 * OUT_DIM);
    }
}

// Round 6
// 291.625 us; speedup vs baseline: 1.4871x; 1.0831x over previous
//
#include <hip/hip_runtime.h>
#include <cstdint>
#include <cstddef>

// Problem constants (fixed shapes from setup_inputs)
#define IN_DIM  1024
#define OUT_DIM 1024
#define NB      7
#define KTOT    8192   // interleaved: k = i*8 + {x, basis0..basis6}
#define BROWS   8192   // batch

typedef unsigned short u16;
typedef __attribute__((ext_vector_type(8))) short bf16x8;
typedef __attribute__((ext_vector_type(8))) unsigned short u16x8;
typedef __attribute__((ext_vector_type(4))) float f32x4;

__device__ __forceinline__ u16 f2bf(float f) {
    union { float f; unsigned int u; } v; v.f = f;
    unsigned int r = (v.u + 0x7fffu + ((v.u >> 16) & 1u)) >> 16;  // RTN-even
    return (u16)r;
}

__device__ __forceinline__ void gl_lds16(const u16* g, u16* l) {
    __builtin_amdgcn_global_load_lds(
        (const __attribute__((address_space(1))) void*)g,
        (__attribute__((address_space(3))) void*)l,
        16, 0, 0);
}

// ---------------------------------------------------------------------------
// prep_wsw: Bt[o][i*8+0] = bf16(W[o][i]); Bt[o][i*8+1+k] = bf16(sw[i][o][k]).
__global__ __launch_bounds__(256) void prep_wsw(const float* __restrict__ sw,
                                                const float* __restrict__ W,
                                                u16* __restrict__ Bt) {
    __shared__ u16 S[8 * 256 * 8];               // [il][ol][slot], 32 KB
    const int i0 = blockIdx.x * 8;
    const int o0 = blockIdx.y * 256;
    const int t  = threadIdx.x;
    #pragma unroll
    for (int il = 0; il < 8; ++il) {
        const float* src = sw + ((size_t)(i0 + il) * OUT_DIM + o0) * NB;
        for (int c = t; c < 256 * NB; c += 256) {
            int ol = c / 7, k = c - ol * 7;
            S[(il * 256 + ol) * 8 + 1 + k] = f2bf(src[c]);
        }
    }
    for (int c = t; c < 2048; c += 256) {
        int ol = c >> 3, il = c & 7;
        S[(il * 256 + ol) * 8] = f2bf(W[(size_t)(o0 + ol) * IN_DIM + i0 + il]);
    }
    __syncthreads();
    for (int c = t; c < 2048; c += 256) {
        int ol = c >> 3, il = c & 7;   // consecutive t -> contiguous 16B writes
        *(u16x8*)&Bt[(size_t)(o0 + ol) * KTOT + (size_t)(i0 + il) * 8] =
            *(const u16x8*)&S[(il * 256 + ol) * 8];
    }
}

// ---------------------------------------------------------------------------
// prep_a: A[b][i*8+0] = bf16(x[b][i]); A[b][i*8+1+k] = bf16(basis_k(tanh(x))).
__global__ __launch_bounds__(256) void prep_a(const float* __restrict__ x,
                                              u16* __restrict__ A, int row0) {
    int gid = blockIdx.x * 256 + threadIdx.x;
    int b = gid >> 10;
    int i = gid & 1023;
    float xv = x[(size_t)(row0 + b) * IN_DIM + i];

    float t = tanhf(xv);
    t = fminf(fmaxf(t, -1.f), 1.f);

    const float kn[11] = {-1.f, -0.8f, -0.6f, -0.4f, -0.2f, 0.f,
                           0.2f, 0.4f, 0.6f, 0.8f, 1.f};
    float bb[8];
    #pragma unroll
    for (int j = 0; j < 7; ++j)
        bb[j] = (t >= kn[j] && t < kn[j + 1]) ? 1.f : 0.f;
    bb[7] = 0.f;

    const float rcp[4] = {0.f, 5.f, 2.5f, 5.f / 3.f};  // 1/(0.2*d)
    #pragma unroll
    for (int d = 1; d <= 3; ++d) {
        #pragma unroll
        for (int j = 0; j < 7; ++j) {
            float left  = (t - kn[j]) * rcp[d];
            float right = (kn[j + d + 1] - t) * rcp[d];
            bb[j] = left * bb[j] + right * bb[j + 1];
        }
    }
    u16x8 outv;
    outv[0] = f2bf(xv);
    #pragma unroll
    for (int k = 0; k < NB; ++k) outv[1 + k] = f2bf(bb[k]);
    *(u16x8*)&A[(size_t)b * KTOT + (size_t)i * 8] = outv;
}

// ---------------------------------------------------------------------------
// gemm_bt v6 = round-5 + BK=64: halves the barrier-drain count (the measured
// ~670 cyc/iter residual), keeping occupancy (32 KB LDS, grid-limited at
// 2 blocks/CU regardless). XOR swizzle over the 8-chunk row:
//   phys_chunk(row, q) = q ^ (row & 7)
// Writer (global_load_lds, slot s = 256g + t): row = 32g + (t>>3), phys = t&7
//   -> logical q = (t&7) ^ ((t>>3)&7)   (g-independent since 32g % 8 == 0)
// Reader (row = ...+lm, logical q = ks*4 + quad): phys = q ^ (lm&7); 16 lanes
// spread over 8 phys chunks = 2-way = free (m136).
__global__ __launch_bounds__(256) void gemm_bt(const u16* __restrict__ A,
                                               const u16* __restrict__ Bt,
                                               const float* __restrict__ bias,
                                               float* __restrict__ C) {
    __shared__ __align__(16) u16 As[128 * 64];   // 16 KB
    __shared__ __align__(16) u16 Bs[128 * 64];   // 16 KB
    const int t = threadIdx.x;
    const int L = t & 63;
    const int w = t >> 6;
    const int wm = w & 1, wn = w >> 1;

    // XCD swizzle: all 8 n-tiles of one m-tile share blockIdx%8 (same XCD)
    const int Lid = blockIdx.x;
    const int n_t = (Lid >> 3) & 7;
    const int m_t = (Lid & 7) + 8 * (Lid >> 6);
    const int m0 = m_t * 128;
    const int n0 = n_t * 128;

    f32x4 acc[4][4] = {};

    // staging: 4 slots per operand per thread; slot s = 256g + t
    const int trow = t >> 3;                   // 0..31
    const int qsw  = (t & 7) ^ (trow & 7);     // logical chunk to fetch
    const u16* gA[4]; const u16* gB[4];
    u16* lA[4]; u16* lB[4];
    #pragma unroll
    for (int g = 0; g < 4; ++g) {
        gA[g] = A  + (size_t)(m0 + 32 * g + trow) * KTOT + qsw * 8;
        gB[g] = Bt + (size_t)(n0 + 32 * g + trow) * KTOT + qsw * 8;
        lA[g] = &As[(256 * g + t) * 8];
        lB[g] = &Bs[(256 * g + t) * 8];
    }

    const int lm  = L & 15;
    const int qd  = L >> 4;                    // quad 0..3

    for (int ko = 0; ko < KTOT; ko += 64) {
        __syncthreads();
        #pragma unroll
        for (int g = 0; g < 4; ++g) gl_lds16(gA[g] + ko, lA[g]);
        #pragma unroll
        for (int g = 0; g < 4; ++g) gl_lds16(gB[g] + ko, lB[g]);
        __syncthreads();

        #pragma unroll
        for (int ks = 0; ks < 2; ++ks) {
            const int pq = ((ks * 4 + qd) ^ (lm & 7)) * 8;
            bf16x8 af[4], bfr[4];
            #pragma unroll
            for (int mi = 0; mi < 4; ++mi)
                af[mi] = *(const bf16x8*)&As[(wm * 64 + mi * 16 + lm) * 64 + pq];
            #pragma unroll
            for (int ni = 0; ni < 4; ++ni)
                bfr[ni] = *(const bf16x8*)&Bs[(wn * 64 + ni * 16 + lm) * 64 + pq];
            #pragma unroll
            for (int mi = 0; mi < 4; ++mi)
                #pragma unroll
                for (int ni = 0; ni < 4; ++ni)
                    acc[mi][ni] = __builtin_amdgcn_mfma_f32_16x16x32_bf16(
                        af[mi], bfr[ni], acc[mi][ni], 0, 0, 0);
        }
    }

    // epilogue: C/D layout col=lane&15, row=(lane>>4)*4+reg (m89-verified)
    const int r0 = qd * 4;
    #pragma unroll
    for (int ni = 0; ni < 4; ++ni) {
        int col = n0 + wn * 64 + ni * 16 + lm;
        float bv = bias[col];
        #pragma unroll
        for (int mi = 0; mi < 4; ++mi) {
            int rb = m0 + wm * 64 + mi * 16 + r0;
            f32x4 v = acc[mi][ni];
            #pragma unroll
            for (int rr = 0; rr < 4; ++rr)
                C[(size_t)(rb + rr) * OUT_DIM + col] = v[rr] + bv;
        }
    }
}

// ---------------------------------------------------------------------------
extern "C" void kernel_launch(void* const* d_in, const int* in_sizes, int n_in,
                              void* d_out, int out_size, void* d_ws, size_t ws_size,
                              hipStream_t stream) {
    (void)in_sizes; (void)n_in; (void)out_size;
    const float* x    = (const float*)d_in[0];
    const float* sw   = (const float*)d_in[1];
    const float* W    = (const float*)d_in[2];
    const float* bias = (const float*)d_in[3];
    float* out = (float*)d_out;

    const size_t btBytes = (size_t)OUT_DIM * KTOT * 2;     // 16 MB
    u16* Bt = (u16*)d_ws;
    u16* A  = (u16*)((char*)d_ws + btBytes);

    prep_wsw<<<dim3(IN_DIM / 8, OUT_DIM / 256), 256, 0, stream>>>(sw, W, Bt);

    int nchunks = 1;
    if (ws_size < btBytes + (size_t)BROWS * KTOT * 2)       nchunks = 2;
    if (ws_size < btBytes + (size_t)(BROWS / 2) * KTOT * 2) nchunks = 4;
    if (ws_size < btBytes + (size_t)(BROWS / 4) * KTOT * 2) nchunks = 8;
    const int rows = BROWS / nchunks;

    for (int c = 0; c < nchunks; ++c) {
        int row0 = c * rows;
        prep_a<<<rows * 4, 256, 0, stream>>>(x, A, row0);
        gemm_bt<<<dim3(8 * (rows / 128)), 256, 0, stream>>>(
            A, Bt, bias, out + (size_t)row0 * OUT_DIM);
    }
}

// Round 7
// 282.299 us; speedup vs baseline: 1.5363x; 1.0330x over previous
//
#include <hip/hip_runtime.h>
#include <cstdint>
#include <cstddef>

// Problem constants (fixed shapes from setup_inputs)
#define IN_DIM  1024
#define OUT_DIM 1024
#define NB      7
#define KTOT    8192   // interleaved: k = i*8 + {x, basis0..basis6}
#define BROWS   8192   // batch

typedef unsigned short u16;
typedef __attribute__((ext_vector_type(8))) short bf16x8;
typedef __attribute__((ext_vector_type(8))) unsigned short u16x8;
typedef __attribute__((ext_vector_type(4))) float f32x4;

__device__ __forceinline__ u16 f2bf(float f) {
    union { float f; unsigned int u; } v; v.f = f;
    unsigned int r = (v.u + 0x7fffu + ((v.u >> 16) & 1u)) >> 16;  // RTN-even
    return (u16)r;
}

__device__ __forceinline__ void gl_lds16(const u16* g, u16* l) {
    __builtin_amdgcn_global_load_lds(
        (const __attribute__((address_space(1))) void*)g,
        (__attribute__((address_space(3))) void*)l,
        16, 0, 0);
}

// ---------------------------------------------------------------------------
// prep_wsw: Bt[o][i*8+0] = bf16(W[o][i]); Bt[o][i*8+1+k] = bf16(sw[i][o][k]).
__global__ __launch_bounds__(256) void prep_wsw(const float* __restrict__ sw,
                                                const float* __restrict__ W,
                                                u16* __restrict__ Bt) {
    __shared__ u16 S[8 * 256 * 8];               // [il][ol][slot], 32 KB
    const int i0 = blockIdx.x * 8;
    const int o0 = blockIdx.y * 256;
    const int t  = threadIdx.x;
    #pragma unroll
    for (int il = 0; il < 8; ++il) {
        const float* src = sw + ((size_t)(i0 + il) * OUT_DIM + o0) * NB;
        for (int c = t; c < 256 * NB; c += 256) {
            int ol = c / 7, k = c - ol * 7;
            S[(il * 256 + ol) * 8 + 1 + k] = f2bf(src[c]);
        }
    }
    for (int c = t; c < 2048; c += 256) {
        int ol = c >> 3, il = c & 7;
        S[(il * 256 + ol) * 8] = f2bf(W[(size_t)(o0 + ol) * IN_DIM + i0 + il]);
    }
    __syncthreads();
    for (int c = t; c < 2048; c += 256) {
        int ol = c >> 3, il = c & 7;   // consecutive t -> contiguous 16B writes
        *(u16x8*)&Bt[(size_t)(o0 + ol) * KTOT + (size_t)(i0 + il) * 8] =
            *(const u16x8*)&S[(il * 256 + ol) * 8];
    }
}

// ---------------------------------------------------------------------------
// prep_a: A[b][i*8+0] = bf16(x[b][i]); A[b][i*8+1+k] = bf16(basis_k(tanh(x))).
// Fast tanh via __expf identity (err ~2^-21, invisible under bf16 rounding).
__global__ __launch_bounds__(256) void prep_a(const float* __restrict__ x,
                                              u16* __restrict__ A, int row0) {
    int gid = blockIdx.x * 256 + threadIdx.x;
    int b = gid >> 10;
    int i = gid & 1023;
    float xv = x[(size_t)(row0 + b) * IN_DIM + i];

    float e = __expf(2.f * xv);
    float t = 1.f - 2.f / (e + 1.f);             // tanh(xv)
    t = fminf(fmaxf(t, -1.f), 1.f);

    const float kn[11] = {-1.f, -0.8f, -0.6f, -0.4f, -0.2f, 0.f,
                           0.2f, 0.4f, 0.6f, 0.8f, 1.f};
    float bb[8];
    #pragma unroll
    for (int j = 0; j < 7; ++j)
        bb[j] = (t >= kn[j] && t < kn[j + 1]) ? 1.f : 0.f;
    bb[7] = 0.f;

    const float rcp[4] = {0.f, 5.f, 2.5f, 5.f / 3.f};  // 1/(0.2*d)
    #pragma unroll
    for (int d = 1; d <= 3; ++d) {
        #pragma unroll
        for (int j = 0; j < 7; ++j) {
            float left  = (t - kn[j]) * rcp[d];
            float right = (kn[j + d + 1] - t) * rcp[d];
            bb[j] = left * bb[j] + right * bb[j + 1];
        }
    }
    u16x8 outv;
    outv[0] = f2bf(xv);
    #pragma unroll
    for (int k = 0; k < NB; ++k) outv[1 + k] = f2bf(bb[k]);
    *(u16x8*)&A[(size_t)b * KTOT + (size_t)i * 8] = outv;
}

// ---------------------------------------------------------------------------
// gemm_bt v7 = v6 + BK=128: halves barrier-pair count again (64 drains).
// Occupancy unchanged: 64 KB LDS/block, 2 blocks/CU (grid-limited anyway;
// 128 KB <= 160 KB). XOR swizzle over 16-chunk rows:
//   phys_chunk(row, q) = q ^ (row & 15)
// Writer slot s = g*256 + t: row = g*16 + (t>>4), phys = t&15
//   -> logical q = (t&15) ^ (t>>4)      (g*16 % 16 == 0)
// Reader row ...+lm, logical q = ks*4 + qd -> phys = q ^ lm  (same verified
// family as v6's 8-chunk swizzle; measured 0 conflicts).
__global__ __launch_bounds__(256) void gemm_bt(const u16* __restrict__ A,
                                               const u16* __restrict__ Bt,
                                               const float* __restrict__ bias,
                                               float* __restrict__ C) {
    __shared__ __align__(16) u16 As[128 * 128];   // 32 KB
    __shared__ __align__(16) u16 Bs[128 * 128];   // 32 KB
    const int t = threadIdx.x;
    const int L = t & 63;
    const int w = t >> 6;
    const int wm = w & 1, wn = w >> 1;

    // XCD swizzle: all 8 n-tiles of one m-tile share blockIdx%8 (same XCD)
    const int Lid = blockIdx.x;
    const int n_t = (Lid >> 3) & 7;
    const int m_t = (Lid & 7) + 8 * (Lid >> 6);
    const int m0 = m_t * 128;
    const int n0 = n_t * 128;

    f32x4 acc[4][4] = {};

    // staging: 8 slots per operand per thread; slot s = g*256 + t
    const int trow = t >> 4;                   // 0..15
    const int qsw  = (t & 15) ^ trow;          // logical chunk to fetch
    const u16* gA[8]; const u16* gB[8];
    u16* lA[8]; u16* lB[8];
    #pragma unroll
    for (int g = 0; g < 8; ++g) {
        gA[g] = A  + (size_t)(m0 + 16 * g + trow) * KTOT + qsw * 8;
        gB[g] = Bt + (size_t)(n0 + 16 * g + trow) * KTOT + qsw * 8;
        lA[g] = &As[(256 * g + t) * 8];
        lB[g] = &Bs[(256 * g + t) * 8];
    }

    const int lm  = L & 15;
    const int qd  = L >> 4;                    // quad 0..3

    for (int ko = 0; ko < KTOT; ko += 128) {
        __syncthreads();
        #pragma unroll
        for (int g = 0; g < 8; ++g) gl_lds16(gA[g] + ko, lA[g]);
        #pragma unroll
        for (int g = 0; g < 8; ++g) gl_lds16(gB[g] + ko, lB[g]);
        __syncthreads();

        #pragma unroll
        for (int ks = 0; ks < 4; ++ks) {
            const int pq = ((ks * 4 + qd) ^ lm) * 8;
            bf16x8 af[4], bfr[4];
            #pragma unroll
            for (int mi = 0; mi < 4; ++mi)
                af[mi] = *(const bf16x8*)&As[(wm * 64 + mi * 16 + lm) * 128 + pq];
            #pragma unroll
            for (int ni = 0; ni < 4; ++ni)
                bfr[ni] = *(const bf16x8*)&Bs[(wn * 64 + ni * 16 + lm) * 128 + pq];
            #pragma unroll
            for (int mi = 0; mi < 4; ++mi)
                #pragma unroll
                for (int ni = 0; ni < 4; ++ni)
                    acc[mi][ni] = __builtin_amdgcn_mfma_f32_16x16x32_bf16(
                        af[mi], bfr[ni], acc[mi][ni], 0, 0, 0);
        }
    }

    // epilogue: C/D layout col=lane&15, row=(lane>>4)*4+reg (m89-verified)
    const int r0 = qd * 4;
    #pragma unroll
    for (int ni = 0; ni < 4; ++ni) {
        int col = n0 + wn * 64 + ni * 16 + lm;
        float bv = bias[col];
        #pragma unroll
        for (int mi = 0; mi < 4; ++mi) {
            int rb = m0 + wm * 64 + mi * 16 + r0;
            f32x4 v = acc[mi][ni];
            #pragma unroll
            for (int rr = 0; rr < 4; ++rr)
                C[(size_t)(rb + rr) * OUT_DIM + col] = v[rr] + bv;
        }
    }
}

// ---------------------------------------------------------------------------
extern "C" void kernel_launch(void* const* d_in, const int* in_sizes, int n_in,
                              void* d_out, int out_size, void* d_ws, size_t ws_size,
                              hipStream_t stream) {
    (void)in_sizes; (void)n_in; (void)out_size;
    const float* x    = (const float*)d_in[0];
    const float* sw   = (const float*)d_in[1];
    const float* W    = (const float*)d_in[2];
    const float* bias = (const float*)d_in[3];
    float* out = (float*)d_out;

    const size_t btBytes = (size_t)OUT_DIM * KTOT * 2;     // 16 MB
    u16* Bt = (u16*)d_ws;
    u16* A  = (u16*)((char*)d_ws + btBytes);

    prep_wsw<<<dim3(IN_DIM / 8, OUT_DIM / 256), 256, 0, stream>>>(sw, W, Bt);

    int nchunks = 1;
    if (ws_size < btBytes + (size_t)BROWS * KTOT * 2)       nchunks = 2;
    if (ws_size < btBytes + (size_t)(BROWS / 2) * KTOT * 2) nchunks = 4;
    if (ws_size < btBytes + (size_t)(BROWS / 4) * KTOT * 2) nchunks = 8;
    const int rows = BROWS / nchunks;

    for (int c = 0; c < nchunks; ++c) {
        int row0 = c * rows;
        prep_a<<<rows * 4, 256, 0, stream>>>(x, A, row0);
        gemm_bt<<<dim3(8 * (rows / 128)), 256, 0, stream>>>(
            A, Bt, bias, out + (size_t)row0 * OUT_DIM);
    }
}